// Round 9
// baseline (536.787 us; speedup 1.0000x reference)
//
#include <hip/hip_runtime.h>
#include <hip/hip_fp8.h>

// ---------------- constants for this problem ----------------
#define EBD   512      // embed size (= head dim here)
#define NHEAD 8
#define BSZ   4
#define SEQ   1024
#define MTOK  4096     // B*S tokens
#define HE    4096     // H*E
#define FFD   2048     // 4*E

typedef __bf16 bf16;
typedef __attribute__((ext_vector_type(4))) float  f32x4;
typedef __attribute__((ext_vector_type(8))) int    i32x8;

// async global->LDS, 16B per lane; LDS dest must be wave-uniform base + lane*16
__device__ __forceinline__ void async_load16(const void* g, void* l) {
  __builtin_amdgcn_global_load_lds(
      (const __attribute__((address_space(1))) void*)g,
      (__attribute__((address_space(3))) void*)l, 16, 0, 0);
}

// ---------------- fp8 e4m3 (OCP) convert helpers ----------------
#if __has_builtin(__builtin_amdgcn_cvt_pk_fp8_f32)
__device__ __forceinline__ int pk_fp8_lo(float a, float b, int old) {
  return __builtin_amdgcn_cvt_pk_fp8_f32(a, b, old, false);
}
__device__ __forceinline__ int pk_fp8_hi(float a, float b, int old) {
  return __builtin_amdgcn_cvt_pk_fp8_f32(a, b, old, true);
}
#else
__device__ __forceinline__ int pk_fp8_lo(float a, float b, int old) {
  __hip_fp8_e4m3 fa(a), fb(b);
  int w = (int)fa.__x | ((int)fb.__x << 8);
  return (old & ~0xffff) | w;
}
__device__ __forceinline__ int pk_fp8_hi(float a, float b, int old) {
  __hip_fp8_e4m3 fa(a), fb(b);
  int w = (int)fa.__x | ((int)fb.__x << 8);
  return (old & 0xffff) | (w << 16);
}
#endif

__device__ __forceinline__ int4 pack16_fp8(const float* v) {
  int4 r;
  r.x = pk_fp8_hi(v[2],  v[3],  pk_fp8_lo(v[0],  v[1],  0));
  r.y = pk_fp8_hi(v[6],  v[7],  pk_fp8_lo(v[4],  v[5],  0));
  r.z = pk_fp8_hi(v[10], v[11], pk_fp8_lo(v[8],  v[9],  0));
  r.w = pk_fp8_hi(v[14], v[15], pk_fp8_lo(v[12], v[13], 0));
  return r;
}

// ---------------- fp8 MX GEMM: C = A @ Bt^T (A: MxK, Bt: NxK, both fp8 e4m3, row-major)
// 128x128 tile, BK=128, mfma_scale_f32_16x16x128_f8f6f4, unit scales (0x7F e8m0).
// A and B staged via global_load_lds (XOR 16B-chunk swizzle, rows = 128 B = bank period).
// SOFTWARE-PIPELINED K-loop (r9): per iteration —
//   barrier(stage kt drained) -> read ALL frags LDS->regs -> barrier(buffer free)
//   -> issue async staging for kt+1 -> 64 MFMAs on regs.
// The prefetch latency drains during the MFMA region instead of stalling the barrier
// (r7 kept MFMA inside the barrier-bounded region: ~2170 cyc/kt vs ~553 MFMA-ideal).
// Epilogue (LDS-staged, coalesced): v = acc*scale + bias[col]; relu optional; modes:
//   0 = fp8 out; 1 = fp8 out exp(v) + atomic row-sum into lsum [scores];
//   2 = fp8 out v/rowdiv[z*SEQ+row] [attn@V]; 3 = fp32 partial stores (split-K).
// vmode: QKV only — col tiles n0>=8192 are V, written transposed as vT[(b*8+h)][e][s] fp8.
__global__ void gemm_f8(const unsigned char* __restrict__ A, const unsigned char* __restrict__ Bt,
                        float* __restrict__ outF, unsigned char* __restrict__ out8,
                        unsigned char* __restrict__ vTout, const float* __restrict__ rowdiv,
                        const float* __restrict__ bias, float* __restrict__ lsum,
                        int lda, int ldb, int ldc, int K,
                        long long bAb, long long bAh, long long bBb, long long bBh,
                        long long bCb, long long bCh, int zdiv,
                        float scale, int mode, int relu, int vmode)
{
  __shared__ __attribute__((aligned(16))) float Smem[4 * 2304];  // 36864 B
  unsigned char* As = (unsigned char*)Smem;       // 128x128 fp8 = 16 KB
  unsigned char* Bs = As + 128 * 128;             // 16 KB (epilogue overlays all of Smem)

  const int t = threadIdx.x;
  const int w = t >> 6, l = t & 63;
  const int m0 = blockIdx.y * 128, n0 = blockIdx.x * 128;
  const int z = blockIdx.z;
  const int zb = z / zdiv, zh = z - zb * zdiv;

  const unsigned char* Ab = A + (size_t)zb * bAb + (size_t)zh * bAh;
  const unsigned char* Bb = Bt + (size_t)zb * bBb + (size_t)zh * bBh;

  // staging: call j: row = j*32+(t>>3), phys chunk t&7 holds global chunk (t&7)^((t>>4)&7)
  const int srow = t >> 3;                              // 0..31
  const int gch  = ((t & 7) ^ ((t >> 4) & 7)) * 16;     // byte offset of 16B chunk
  const unsigned char* pA = Ab + (size_t)(m0 + srow) * lda + gch;
  const unsigned char* pB = Bb + (size_t)(n0 + srow) * ldb + gch;
  const size_t ldA32 = (size_t)32 * lda;
  const size_t ldB32 = (size_t)32 * ldb;

  unsigned char* ldsA = As + w * 1024;   // + j*4096 per call
  unsigned char* ldsB = Bs + w * 1024;

  const int wm = (w >> 1) * 64, wn = (w & 1) * 64;
  const int lr = l & 15;                 // row within 16
  const int lg = l >> 4;                 // 32-byte k-group (0..3)

  f32x4 acc[4][4];
#pragma unroll
  for (int i = 0; i < 4; ++i)
#pragma unroll
    for (int j = 0; j < 4; ++j) { f32x4 zv = {0.f, 0.f, 0.f, 0.f}; acc[i][j] = zv; }

  const int nkt = K >> 7;                // BK=128
  // prologue: stage kt=0
#pragma unroll
  for (int j = 0; j < 4; ++j) {
    async_load16(pA + j * ldA32, ldsA + j * 4096);
    async_load16(pB + j * ldB32, ldsB + j * 4096);
  }
  pA += 128; pB += 128;

  for (int kt = 0; kt < nkt; ++kt) {
    __syncthreads();                     // stage kt complete (vmcnt drained)
    i32x8 af[4], bv[4];
#pragma unroll
    for (int i = 0; i < 4; ++i) {
      const int row = wm + i * 16 + lr;
      const int s = (row >> 1) & 7;
      const int c0 = (2 * lg) ^ s, c1 = (2 * lg + 1) ^ s;
      const int4 lo = *(const int4*)&As[row * 128 + c0 * 16];
      const int4 hi = *(const int4*)&As[row * 128 + c1 * 16];
      i32x8 v = {lo.x, lo.y, lo.z, lo.w, hi.x, hi.y, hi.z, hi.w};
      af[i] = v;
    }
#pragma unroll
    for (int i = 0; i < 4; ++i) {
      const int row = wn + i * 16 + lr;
      const int s = (row >> 1) & 7;
      const int c0 = (2 * lg) ^ s, c1 = (2 * lg + 1) ^ s;
      const int4 lo = *(const int4*)&Bs[row * 128 + c0 * 16];
      const int4 hi = *(const int4*)&Bs[row * 128 + c1 * 16];
      i32x8 v = {lo.x, lo.y, lo.z, lo.w, hi.x, hi.y, hi.z, hi.w};
      bv[i] = v;
    }
    __syncthreads();                     // all LDS reads done -> buffer reusable
    if (kt + 1 < nkt) {                  // prefetch kt+1; drains during MFMA region
#pragma unroll
      for (int j = 0; j < 4; ++j) {
        async_load16(pA + j * ldA32, ldsA + j * 4096);
        async_load16(pB + j * ldB32, ldsB + j * 4096);
      }
      pA += 128; pB += 128;
    }
#pragma unroll
    for (int mi = 0; mi < 4; ++mi)
#pragma unroll
      for (int ni = 0; ni < 4; ++ni)
        acc[mi][ni] = __builtin_amdgcn_mfma_scale_f32_16x16x128_f8f6f4(
            af[mi], bv[ni], acc[mi][ni], 0, 0, 0, 0x7f7f7f7f, 0, 0x7f7f7f7f);
  }

  // ---- LDS-staged epilogue (C/D 16x16 layout: col=lane&15, row=(lane>>4)*4+r) ----
  float* cs = Smem + w * 2304;
  const size_t offC = (size_t)zb * bCb + (size_t)zh * bCh;
  const int rq = (l >> 4) * 4;

  if (vmode && n0 >= 8192) {
    // V-projection tiles: store transposed into vT[(b*8+h)][e][s], fp8
    const int b8 = (m0 + wm) >> 10;
    const int s0 = (m0 + wm) & 1023;
#pragma unroll
    for (int ph = 0; ph < 2; ++ph) {
      __syncthreads();
#pragma unroll
      for (int ni2 = 0; ni2 < 2; ++ni2) {
        const int ni = 2 * ph + ni2;
        const int cl = ni2 * 16 + lr;
#pragma unroll
        for (int mi = 0; mi < 4; ++mi)
#pragma unroll
          for (int r = 0; r < 4; ++r)
            cs[cl * 68 + mi * 16 + rq + r] = acc[mi][ni][r];  // transposed: [col][row]
      }
      __syncthreads();
      const int c = l & 31, half = l >> 5;
      int e = (n0 - 8192) + wn + ph * 32 + c;
      const int h = e >> 9; e &= 511;
      unsigned char* dst = vTout + (((size_t)(b8 * 8 + h) * 512 + e) << 10) + s0 + half * 32;
      float vv[32];
#pragma unroll
      for (int j = 0; j < 8; ++j)
        *(f32x4*)&vv[4 * j] = *(const f32x4*)&cs[c * 68 + half * 32 + 4 * j];
#pragma unroll
      for (int j = 0; j < 32; ++j) vv[j] *= scale;
      *(int4*)dst        = pack16_fp8(&vv[0]);
      *(int4*)(dst + 16) = pack16_fp8(&vv[16]);
    }
    return;
  }

  const int rl0 = l >> 1, c16 = (l & 1) * 16;   // fp8-out lane map
  float rsum[2] = {0.f, 0.f};                   // mode-1 per-row partial sums

#pragma unroll
  for (int ph = 0; ph < 2; ++ph) {
    __syncthreads();
#pragma unroll
    for (int ni2 = 0; ni2 < 2; ++ni2) {
      const int ni = 2 * ph + ni2;
      const int cl = ni2 * 16 + lr;
#pragma unroll
      for (int mi = 0; mi < 4; ++mi)
#pragma unroll
        for (int r = 0; r < 4; ++r)
          cs[(mi * 16 + rq + r) * 36 + cl] = acc[mi][ni][r];
    }
    __syncthreads();
    if (mode == 3) {
      // fp32 split-K partials
      const int prl0 = l >> 3, c4 = (l & 7) * 4;
#pragma unroll
      for (int sub = 0; sub < 8; ++sub) {
        const int rl = sub * 8 + prl0;
        const int rowg = m0 + wm + rl;
        const int colg = n0 + wn + ph * 32 + c4;
        float4 v = *(const float4*)&cs[rl * 36 + c4];
        v.x *= scale; v.y *= scale; v.z *= scale; v.w *= scale;
        *(float4*)(outF + offC + (size_t)rowg * ldc + colg) = v;
      }
    } else {
      // fp8 output: lane packs 16 consecutive cols of one row -> 16B store
#pragma unroll
      for (int sub = 0; sub < 2; ++sub) {
        const int rl = sub * 32 + rl0;
        const int rowg = m0 + wm + rl;
        const int colg = n0 + wn + ph * 32 + c16;
        float vv[16];
#pragma unroll
        for (int j2 = 0; j2 < 4; ++j2)
          *(f32x4*)&vv[4 * j2] = *(const f32x4*)&cs[rl * 36 + c16 + 4 * j2];
#pragma unroll
        for (int j = 0; j < 16; ++j) vv[j] *= scale;
        if (bias) {
#pragma unroll
          for (int j2 = 0; j2 < 4; ++j2) {
            const float4 b0 = *(const float4*)(bias + colg + 4 * j2);
            vv[4 * j2] += b0.x; vv[4 * j2 + 1] += b0.y;
            vv[4 * j2 + 2] += b0.z; vv[4 * j2 + 3] += b0.w;
          }
        }
        if (relu)
#pragma unroll
          for (int j = 0; j < 16; ++j) vv[j] = fmaxf(vv[j], 0.0f);
        if (mode == 1) {
          float s = 0.0f;
#pragma unroll
          for (int j = 0; j < 16; ++j) { vv[j] = __expf(vv[j]); s += vv[j]; }
          rsum[sub] += s;
        } else if (mode == 2) {
          const float d = 1.0f / rowdiv[(size_t)z * SEQ + rowg];
#pragma unroll
          for (int j = 0; j < 16; ++j) vv[j] *= d;
        }
        *(int4*)(out8 + offC + (size_t)rowg * ldc + colg) = pack16_fp8(vv);
      }
    }
  }
  if (mode == 1 && lsum) {
    // lanes l and l^1 hold the same row; combine, one atomic per pair
#pragma unroll
    for (int sub = 0; sub < 2; ++sub) {
      float s = rsum[sub] + __shfl_xor(rsum[sub], 1);
      if (!(l & 1)) {
        const int rowg = m0 + wm + sub * 32 + rl0;
        atomicAdd(&lsum[(size_t)z * SEQ + rowg], s);
      }
    }
  }
}

// ---------------- cast x (fp32 -> fp8 e4m3), 16 elems/thread; last block zeroes lsum ----------------
__global__ void cast_x_f8(const float* __restrict__ in, unsigned char* __restrict__ out,
                          int n16, float* __restrict__ lsum) {
  int i = blockIdx.x * 256 + threadIdx.x;
  if (i >= n16) {
    if (blockIdx.x == (unsigned)(n16 / 256)) {   // the extra tail block
      float4 zv = {0.f, 0.f, 0.f, 0.f};
      float4* q = (float4*)lsum;                 // 32*SEQ floats = 8192 float4
#pragma unroll
      for (int j = 0; j < 32; ++j) q[threadIdx.x * 32 + j] = zv;
    }
    return;
  }
  const float4* p = (const float4*)in + (size_t)i * 4;
  float vv[16];
  *(f32x4*)&vv[0]  = *(const f32x4*)&p[0];
  *(f32x4*)&vv[4]  = *(const f32x4*)&p[1];
  *(f32x4*)&vv[8]  = *(const f32x4*)&p[2];
  *(f32x4*)&vv[12] = *(const f32x4*)&p[3];
  ((int4*)out)[i] = pack16_fp8(vv);
}

// ---------------- batched weight transpose+cast: fp32 [K][N] -> fp8 [N][K], 6 weights ----------------
struct WTList {
  const float* in[6];
  unsigned char* out[6];
  float scale[6];
  int K[6], N[6];
  int start[7];   // prefix sums of block counts
};
__global__ void transpose_cast_all(WTList L) {
  __shared__ float tile[32][33];
  int bid = blockIdx.x;
  int i = 0;
  while (bid >= L.start[i + 1]) ++i;
  int rel = bid - L.start[i];
  const int N = L.N[i], K = L.K[i];
  const int nx = N >> 5;
  const int n0 = (rel % nx) * 32, k0 = (rel / nx) * 32;
  const float* in = L.in[i];
  const float sc = L.scale[i];
  unsigned char* out = L.out[i];
  int tx = threadIdx.x, ty = threadIdx.y;
#pragma unroll
  for (int j = 0; j < 32; j += 8)
    tile[ty + j][tx] = in[(size_t)(k0 + ty + j) * N + n0 + tx];
  __syncthreads();
#pragma unroll
  for (int j = 0; j < 32; j += 8)
    out[(size_t)(n0 + ty + j) * K + k0 + tx] =
        (unsigned char)(pk_fp8_lo(tile[tx][ty + j] * sc, 0.f, 0) & 0xff);
}

// ---------------- split-K reduce + residual + bias + layernorm, one wave per row ----------------
__global__ void reduce_ln(const float* __restrict__ parts, int ns,
                          const float* __restrict__ res, const float* __restrict__ bias,
                          const float* __restrict__ gw, const float* __restrict__ bw,
                          float* __restrict__ outF, unsigned char* __restrict__ out8) {
  int l = threadIdx.x & 63, w = threadIdx.x >> 6;
  int row = blockIdx.x * 4 + w;
  const long long pstr = (long long)MTOK * EBD;
  float4 a = {0.f, 0.f, 0.f, 0.f}, b = {0.f, 0.f, 0.f, 0.f};
  for (int s = 0; s < ns; ++s) {
    const float4* p = (const float4*)(parts + s * pstr + (size_t)row * EBD);
    float4 pa = p[l], pb = p[l + 64];
    a.x += pa.x; a.y += pa.y; a.z += pa.z; a.w += pa.w;
    b.x += pb.x; b.y += pb.y; b.z += pb.z; b.w += pb.w;
  }
  {
    const float4* p = (const float4*)(res + (size_t)row * EBD);
    float4 pa = p[l], pb = p[l + 64];
    a.x += pa.x; a.y += pa.y; a.z += pa.z; a.w += pa.w;
    b.x += pb.x; b.y += pb.y; b.z += pb.z; b.w += pb.w;
  }
  if (bias) {
    const float4* p = (const float4*)bias;
    float4 pa = p[l], pb = p[l + 64];
    a.x += pa.x; a.y += pa.y; a.z += pa.z; a.w += pa.w;
    b.x += pb.x; b.y += pb.y; b.z += pb.z; b.w += pb.w;
  }
  float s = a.x + a.y + a.z + a.w + b.x + b.y + b.z + b.w;
  float q = a.x * a.x + a.y * a.y + a.z * a.z + a.w * a.w
          + b.x * b.x + b.y * b.y + b.z * b.z + b.w * b.w;
#pragma unroll
  for (int d = 1; d < 64; d <<= 1) { s += __shfl_xor(s, d); q += __shfl_xor(q, d); }
  float mu = s * (1.0f / EBD);
  float var = q * (1.0f / EBD) - mu * mu;
  float rs = rsqrtf(var + 1e-5f);
  const float4* g4 = (const float4*)gw;
  const float4* b4 = (const float4*)bw;
  float4 ga = g4[l], gb = g4[l + 64], ba = b4[l], bb = b4[l + 64];
  float4 o0, o1;
  o0.x = (a.x - mu) * rs * ga.x + ba.x;
  o0.y = (a.y - mu) * rs * ga.y + ba.y;
  o0.z = (a.z - mu) * rs * ga.z + ba.z;
  o0.w = (a.w - mu) * rs * ga.w + ba.w;
  o1.x = (b.x - mu) * rs * gb.x + bb.x;
  o1.y = (b.y - mu) * rs * gb.y + bb.y;
  o1.z = (b.z - mu) * rs * gb.z + bb.z;
  o1.w = (b.w - mu) * rs * gb.w + bb.w;
  if (outF) {
    float4* q4 = (float4*)(outF + (size_t)row * EBD);
    q4[l] = o0; q4[l + 64] = o1;
  }
  if (out8) {
    int* o = (int*)(out8 + (size_t)row * EBD);
    o[l]      = pk_fp8_hi(o0.z, o0.w, pk_fp8_lo(o0.x, o0.y, 0));
    o[l + 64] = pk_fp8_hi(o1.z, o1.w, pk_fp8_lo(o1.x, o1.y, 0));
  }
}

// ---------------- host-side orchestration ----------------
extern "C" void kernel_launch(void* const* d_in, const int* in_sizes, int n_in,
                              void* d_out, int out_size, void* d_ws, size_t ws_size,
                              hipStream_t stream) {
  const float* x  = (const float*)d_in[0];
  const float* Wq = (const float*)d_in[1];
  const float* Wk = (const float*)d_in[2];
  const float* Wv = (const float*)d_in[3];
  const float* Wo = (const float*)d_in[4];
  const float* g1 = (const float*)d_in[5];
  const float* b1 = (const float*)d_in[6];
  const float* g2 = (const float*)d_in[7];
  const float* b2 = (const float*)d_in[8];
  const float* W1 = (const float*)d_in[9];
  const float* c1 = (const float*)d_in[10];
  const float* W2 = (const float*)d_in[11];
  const float* c2 = (const float*)d_in[12];
  float* out = (float*)d_out;

  char* p = (char*)d_ws;
  auto take = [&](size_t bytes) { char* r = p; p += (bytes + 255) & ~(size_t)255; return r; };
  unsigned char* xb8    = (unsigned char*)take((size_t)MTOK * EBD);        //  2 MB
  unsigned char* qk8    = (unsigned char*)take((size_t)MTOK * 2 * HE);     // 32 MB [4096][8192]
  unsigned char* vT8    = (unsigned char*)take((size_t)32 * EBD * SEQ);    // 16 MB [(b,h)][e][s]
  unsigned char* sc8    = (unsigned char*)take((size_t)32 * SEQ * SEQ);    // 32 MB exp-scores (fp32 partials overlay later)
  float*         lsum   = (float*)        take((size_t)32 * SEQ * 4);      // 128 KB row sums
  unsigned char* ao8    = (unsigned char*)take((size_t)MTOK * HE);         // 16 MB O*16
  float*         nF     = (float*)        take((size_t)MTOK * EBD * 4);    //  8 MB
  unsigned char* n8     = (unsigned char*)take((size_t)MTOK * EBD);        //  2 MB
  unsigned char* h8     = (unsigned char*)take((size_t)MTOK * FFD);        //  8 MB
  unsigned char* Wqkv8T = (unsigned char*)take((size_t)3 * HE * EBD);      //  6 MB [12288][512]
  unsigned char* Wo8T   = (unsigned char*)take((size_t)EBD * HE);          //  2 MB [512][4096]
  unsigned char* W18T   = (unsigned char*)take((size_t)FFD * EBD);         //  1 MB [2048][512]
  unsigned char* W28T   = (unsigned char*)take((size_t)EBD * FFD);         //  1 MB [512][2048]
  float* parts = (float*)sc8;   // 32 MB fp32 split-K partials (sc8 dead after attn@V)

  auto gemmf8 = [&](const unsigned char* A, const unsigned char* Bt, float* oF,
                    unsigned char* o8, unsigned char* vTo, const float* rdiv,
                    const float* bias_, float* lsum_,
                    int Mm, int Nn, int Kk, int lda_, int ldb_, int ldc_,
                    long long bAb, long long bAh, long long bBb, long long bBh,
                    long long bCb, long long bCh, int zdiv_, int batch,
                    float sc_, int mode_, int relu_, int vmode_) {
    dim3 g(Nn / 128, Mm / 128, batch);
    gemm_f8<<<g, dim3(256), 0, stream>>>(A, Bt, oF, o8, vTo, rdiv, bias_, lsum_,
        lda_, ldb_, ldc_, Kk, bAb, bAh, bBb, bBh, bCb, bCh, zdiv_, sc_, mode_, relu_, vmode_);
  };

  // --- preprocessing: x -> fp8 (+ zero lsum); weights -> fp8 transposed (scaled) ---
  cast_x_f8<<<dim3(MTOK * EBD / 16 / 256 + 1), dim3(256), 0, stream>>>(
      x, xb8, MTOK * EBD / 16, lsum);
  {
    WTList L;
    const float* ins[6] = {Wq, Wk, Wv, Wo, W1, W2};
    unsigned char* outs[6] = {Wqkv8T, Wqkv8T + (size_t)HE * EBD, Wqkv8T + (size_t)2 * HE * EBD,
                              Wo8T, W18T, W28T};
    float scs[6] = {8.f, 8.f, 8.f, 16.f, 8.f, 16.f};
    int Ks[6] = {EBD, EBD, EBD, HE, EBD, FFD};
    int Ns[6] = {HE, HE, HE, EBD, FFD, EBD};
    int acc = 0;
    for (int i = 0; i < 6; ++i) {
      L.in[i] = ins[i]; L.out[i] = outs[i]; L.scale[i] = scs[i];
      L.K[i] = Ks[i]; L.N[i] = Ns[i]; L.start[i] = acc;
      acc += (Ks[i] / 32) * (Ns[i] / 32);
    }
    L.start[6] = acc;
    transpose_cast_all<<<dim3(acc), dim3(32, 8), 0, stream>>>(L);
  }

  // --- fused QKV (fp8): q,k -> qk8 [4096][8192]; V -> vT8 transposed; scale 1/8 ---
  gemmf8(xb8, Wqkv8T, nullptr, qk8, vT8, nullptr, nullptr, nullptr,
         MTOK, 3 * HE, EBD, EBD, EBD, 2 * HE,
         0, 0, 0, 0, 0, 0, 64, 1, 0.125f, 0, 0, 1);

  // --- exp-scores = exp(q.k/sqrt(E)) fp8 + atomic row sums, batched over 32 (b,h) ---
  const float qs = 0.04419417382415922f;  // 1/sqrt(512)
  gemmf8(qk8, qk8 + HE, nullptr, sc8, nullptr, nullptr, nullptr, lsum,
         SEQ, SEQ, EBD, 2 * HE, 2 * HE, SEQ,
         (long long)SEQ * 2 * HE, EBD, (long long)SEQ * 2 * HE, EBD,
         (long long)8 * SEQ * SEQ, (long long)SEQ * SEQ, 8, 32, qs, 1, 0, 0);

  // --- O = (exp-scores @ v) * 16 / l, fp8 out into ao8 [token][h*512+e] ---
  gemmf8(sc8, vT8, nullptr, ao8, nullptr, lsum, nullptr, nullptr,
         SEQ, EBD, SEQ, SEQ, SEQ, HE,
         (long long)8 * SEQ * SEQ, (long long)SEQ * SEQ,
         (long long)8 * EBD * SEQ, (long long)EBD * SEQ,
         (long long)SEQ * HE, (long long)EBD, 8, 32, 16.0f, 2, 0, 0);

  // --- O16 @ Wo16^T, split-K x4 (K=4096) -> fp32 partials (scale 1/256); reduce + x + LN1 ---
  gemmf8(ao8, Wo8T, parts, nullptr, nullptr, nullptr, nullptr, nullptr,
         MTOK, EBD, 1024, HE, HE, EBD,
         0, 1024, 0, 1024, 0, (long long)MTOK * EBD, 64, 4, 1.0f / 256.0f, 3, 0, 0);
  reduce_ln<<<dim3(MTOK / 4), dim3(256), 0, stream>>>(parts, 4, x, nullptr, g1, b1, nF, n8);

  // --- FF1 (fp8): h = relu(n @ W1x8 /8 + c1) -> h8 ---
  gemmf8(n8, W18T, nullptr, h8, nullptr, nullptr, c1, nullptr,
         MTOK, FFD, EBD, EBD, EBD, FFD,
         0, 0, 0, 0, 0, 0, 64, 1, 0.125f, 0, 1, 0);

  // --- FF2 (fp8): h8 @ W2x16, split-K x4 (K=2048) -> partials (scale 1/16); reduce + c2 + nF + LN2 ---
  gemmf8(h8, W28T, parts, nullptr, nullptr, nullptr, nullptr, nullptr,
         MTOK, EBD, 512, FFD, FFD, EBD,
         0, 512, 0, 512, 0, (long long)MTOK * EBD, 64, 4, 1.0f / 16.0f, 3, 0, 0);
  reduce_ln<<<dim3(MTOK / 4), dim3(256), 0, stream>>>(parts, 4, nF, c2, g2, b2, out, nullptr);
}

// Round 10
// 272.398 us; speedup vs baseline: 1.9706x; 1.9706x over previous
//
#include <hip/hip_runtime.h>
#include <hip/hip_fp8.h>

// ---------------- constants for this problem ----------------
#define EBD   512      // embed size (= head dim here)
#define NHEAD 8
#define BSZ   4
#define SEQ   1024
#define MTOK  4096     // B*S tokens
#define HE    4096     // H*E
#define FFD   2048     // 4*E

typedef __bf16 bf16;
typedef __attribute__((ext_vector_type(4))) float  f32x4;
typedef __attribute__((ext_vector_type(8))) int    i32x8;

// async global->LDS, 16B per lane; LDS dest must be wave-uniform base + lane*16
__device__ __forceinline__ void async_load16(const void* g, void* l) {
  __builtin_amdgcn_global_load_lds(
      (const __attribute__((address_space(1))) void*)g,
      (__attribute__((address_space(3))) void*)l, 16, 0, 0);
}

// ---------------- fp8 e4m3 (OCP) convert helpers ----------------
#if __has_builtin(__builtin_amdgcn_cvt_pk_fp8_f32)
__device__ __forceinline__ int pk_fp8_lo(float a, float b, int old) {
  return __builtin_amdgcn_cvt_pk_fp8_f32(a, b, old, false);
}
__device__ __forceinline__ int pk_fp8_hi(float a, float b, int old) {
  return __builtin_amdgcn_cvt_pk_fp8_f32(a, b, old, true);
}
#else
__device__ __forceinline__ int pk_fp8_lo(float a, float b, int old) {
  __hip_fp8_e4m3 fa(a), fb(b);
  int w = (int)fa.__x | ((int)fb.__x << 8);
  return (old & ~0xffff) | w;
}
__device__ __forceinline__ int pk_fp8_hi(float a, float b, int old) {
  __hip_fp8_e4m3 fa(a), fb(b);
  int w = (int)fa.__x | ((int)fb.__x << 8);
  return (old & 0xffff) | (w << 16);
}
#endif

__device__ __forceinline__ int4 pack16_fp8(const float* v) {
  int4 r;
  r.x = pk_fp8_hi(v[2],  v[3],  pk_fp8_lo(v[0],  v[1],  0));
  r.y = pk_fp8_hi(v[6],  v[7],  pk_fp8_lo(v[4],  v[5],  0));
  r.z = pk_fp8_hi(v[10], v[11], pk_fp8_lo(v[8],  v[9],  0));
  r.w = pk_fp8_hi(v[14], v[15], pk_fp8_lo(v[12], v[13], 0));
  return r;
}

// ---------------- fp8 MX GEMM: C = A @ Bt^T (A: MxK, Bt: NxK, both fp8 e4m3, row-major)
// 128x128 tile, BK=128, mfma_scale_f32_16x16x128_f8f6f4, unit scales (0x7F e8m0).
// A and B staged via global_load_lds (XOR 16B-chunk swizzle, rows = 128 B = bank period).
// SOFTWARE-PIPELINED K-loop: barrier(stage kt drained) -> read ALL frags LDS->regs ->
// barrier(buffer free) -> issue async staging for kt+1 -> 64 MFMAs on regs.
// __launch_bounds__(256, 2): r9 ran this pipeline without bounds, the allocator kept
// 64 arch VGPRs and spilled the 64 fragment regs to scratch (374 MB WRITE_SIZE, 125 us
// dispatch). 2 waves/EU min -> <=256 VGPRs/wave, ~170 needed incl. acc -> no spill,
// 2 blocks/CU; in-block prefetch replaces the lost TLP.
// Epilogue (LDS-staged, coalesced): v = acc*scale + bias[col]; relu optional; modes:
//   0 = fp8 out; 1 = fp8 out exp(v) + atomic row-sum into lsum [scores];
//   2 = fp8 out v/rowdiv[z*SEQ+row] [attn@V]; 3 = fp32 partial stores (split-K).
// vmode: QKV only — col tiles n0>=8192 are V, written transposed as vT[(b*8+h)][e][s] fp8.
__global__ void __launch_bounds__(256, 2)
gemm_f8(const unsigned char* __restrict__ A, const unsigned char* __restrict__ Bt,
        float* __restrict__ outF, unsigned char* __restrict__ out8,
        unsigned char* __restrict__ vTout, const float* __restrict__ rowdiv,
        const float* __restrict__ bias, float* __restrict__ lsum,
        int lda, int ldb, int ldc, int K,
        long long bAb, long long bAh, long long bBb, long long bBh,
        long long bCb, long long bCh, int zdiv,
        float scale, int mode, int relu, int vmode)
{
  __shared__ __attribute__((aligned(16))) float Smem[4 * 2304];  // 36864 B
  unsigned char* As = (unsigned char*)Smem;       // 128x128 fp8 = 16 KB
  unsigned char* Bs = As + 128 * 128;             // 16 KB (epilogue overlays all of Smem)

  const int t = threadIdx.x;
  const int w = t >> 6, l = t & 63;
  const int m0 = blockIdx.y * 128, n0 = blockIdx.x * 128;
  const int z = blockIdx.z;
  const int zb = z / zdiv, zh = z - zb * zdiv;

  const unsigned char* Ab = A + (size_t)zb * bAb + (size_t)zh * bAh;
  const unsigned char* Bb = Bt + (size_t)zb * bBb + (size_t)zh * bBh;

  // staging: call j: row = j*32+(t>>3), phys chunk t&7 holds global chunk (t&7)^((t>>4)&7)
  const int srow = t >> 3;                              // 0..31
  const int gch  = ((t & 7) ^ ((t >> 4) & 7)) * 16;     // byte offset of 16B chunk
  const unsigned char* pA = Ab + (size_t)(m0 + srow) * lda + gch;
  const unsigned char* pB = Bb + (size_t)(n0 + srow) * ldb + gch;
  const size_t ldA32 = (size_t)32 * lda;
  const size_t ldB32 = (size_t)32 * ldb;

  unsigned char* ldsA = As + w * 1024;   // + j*4096 per call
  unsigned char* ldsB = Bs + w * 1024;

  const int wm = (w >> 1) * 64, wn = (w & 1) * 64;
  const int lr = l & 15;                 // row within 16
  const int lg = l >> 4;                 // 32-byte k-group (0..3)

  f32x4 acc[4][4];
#pragma unroll
  for (int i = 0; i < 4; ++i)
#pragma unroll
    for (int j = 0; j < 4; ++j) { f32x4 zv = {0.f, 0.f, 0.f, 0.f}; acc[i][j] = zv; }

  const int nkt = K >> 7;                // BK=128
  // prologue: stage kt=0
#pragma unroll
  for (int j = 0; j < 4; ++j) {
    async_load16(pA + j * ldA32, ldsA + j * 4096);
    async_load16(pB + j * ldB32, ldsB + j * 4096);
  }
  pA += 128; pB += 128;

  for (int kt = 0; kt < nkt; ++kt) {
    __syncthreads();                     // stage kt complete (vmcnt drained)
    i32x8 af[4], bv[4];
#pragma unroll
    for (int i = 0; i < 4; ++i) {
      const int row = wm + i * 16 + lr;
      const int s = (row >> 1) & 7;
      const int c0 = (2 * lg) ^ s, c1 = (2 * lg + 1) ^ s;
      const int4 lo = *(const int4*)&As[row * 128 + c0 * 16];
      const int4 hi = *(const int4*)&As[row * 128 + c1 * 16];
      i32x8 v = {lo.x, lo.y, lo.z, lo.w, hi.x, hi.y, hi.z, hi.w};
      af[i] = v;
    }
#pragma unroll
    for (int i = 0; i < 4; ++i) {
      const int row = wn + i * 16 + lr;
      const int s = (row >> 1) & 7;
      const int c0 = (2 * lg) ^ s, c1 = (2 * lg + 1) ^ s;
      const int4 lo = *(const int4*)&Bs[row * 128 + c0 * 16];
      const int4 hi = *(const int4*)&Bs[row * 128 + c1 * 16];
      i32x8 v = {lo.x, lo.y, lo.z, lo.w, hi.x, hi.y, hi.z, hi.w};
      bv[i] = v;
    }
    __syncthreads();                     // all LDS reads done -> buffer reusable
    if (kt + 1 < nkt) {                  // prefetch kt+1; drains during MFMA region
#pragma unroll
      for (int j = 0; j < 4; ++j) {
        async_load16(pA + j * ldA32, ldsA + j * 4096);
        async_load16(pB + j * ldB32, ldsB + j * 4096);
      }
      pA += 128; pB += 128;
    }
#pragma unroll
    for (int mi = 0; mi < 4; ++mi)
#pragma unroll
      for (int ni = 0; ni < 4; ++ni)
        acc[mi][ni] = __builtin_amdgcn_mfma_scale_f32_16x16x128_f8f6f4(
            af[mi], bv[ni], acc[mi][ni], 0, 0, 0, 0x7f7f7f7f, 0, 0x7f7f7f7f);
  }

  // ---- LDS-staged epilogue (C/D 16x16 layout: col=lane&15, row=(lane>>4)*4+r) ----
  float* cs = Smem + w * 2304;
  const size_t offC = (size_t)zb * bCb + (size_t)zh * bCh;
  const int rq = (l >> 4) * 4;

  if (vmode && n0 >= 8192) {
    // V-projection tiles: store transposed into vT[(b*8+h)][e][s], fp8
    const int b8 = (m0 + wm) >> 10;
    const int s0 = (m0 + wm) & 1023;
#pragma unroll
    for (int ph = 0; ph < 2; ++ph) {
      __syncthreads();
#pragma unroll
      for (int ni2 = 0; ni2 < 2; ++ni2) {
        const int ni = 2 * ph + ni2;
        const int cl = ni2 * 16 + lr;
#pragma unroll
        for (int mi = 0; mi < 4; ++mi)
#pragma unroll
          for (int r = 0; r < 4; ++r)
            cs[cl * 68 + mi * 16 + rq + r] = acc[mi][ni][r];  // transposed: [col][row]
      }
      __syncthreads();
      const int c = l & 31, half = l >> 5;
      int e = (n0 - 8192) + wn + ph * 32 + c;
      const int h = e >> 9; e &= 511;
      unsigned char* dst = vTout + (((size_t)(b8 * 8 + h) * 512 + e) << 10) + s0 + half * 32;
      float vv[32];
#pragma unroll
      for (int j = 0; j < 8; ++j)
        *(f32x4*)&vv[4 * j] = *(const f32x4*)&cs[c * 68 + half * 32 + 4 * j];
#pragma unroll
      for (int j = 0; j < 32; ++j) vv[j] *= scale;
      *(int4*)dst        = pack16_fp8(&vv[0]);
      *(int4*)(dst + 16) = pack16_fp8(&vv[16]);
    }
    return;
  }

  const int rl0 = l >> 1, c16 = (l & 1) * 16;   // fp8-out lane map
  float rsum[2] = {0.f, 0.f};                   // mode-1 per-row partial sums

#pragma unroll
  for (int ph = 0; ph < 2; ++ph) {
    __syncthreads();
#pragma unroll
    for (int ni2 = 0; ni2 < 2; ++ni2) {
      const int ni = 2 * ph + ni2;
      const int cl = ni2 * 16 + lr;
#pragma unroll
      for (int mi = 0; mi < 4; ++mi)
#pragma unroll
        for (int r = 0; r < 4; ++r)
          cs[(mi * 16 + rq + r) * 36 + cl] = acc[mi][ni][r];
    }
    __syncthreads();
    if (mode == 3) {
      // fp32 split-K partials
      const int prl0 = l >> 3, c4 = (l & 7) * 4;
#pragma unroll
      for (int sub = 0; sub < 8; ++sub) {
        const int rl = sub * 8 + prl0;
        const int rowg = m0 + wm + rl;
        const int colg = n0 + wn + ph * 32 + c4;
        float4 v = *(const float4*)&cs[rl * 36 + c4];
        v.x *= scale; v.y *= scale; v.z *= scale; v.w *= scale;
        *(float4*)(outF + offC + (size_t)rowg * ldc + colg) = v;
      }
    } else {
      // fp8 output: lane packs 16 consecutive cols of one row -> 16B store
#pragma unroll
      for (int sub = 0; sub < 2; ++sub) {
        const int rl = sub * 32 + rl0;
        const int rowg = m0 + wm + rl;
        const int colg = n0 + wn + ph * 32 + c16;
        float vv[16];
#pragma unroll
        for (int j2 = 0; j2 < 4; ++j2)
          *(f32x4*)&vv[4 * j2] = *(const f32x4*)&cs[rl * 36 + c16 + 4 * j2];
#pragma unroll
        for (int j = 0; j < 16; ++j) vv[j] *= scale;
        if (bias) {
#pragma unroll
          for (int j2 = 0; j2 < 4; ++j2) {
            const float4 b0 = *(const float4*)(bias + colg + 4 * j2);
            vv[4 * j2] += b0.x; vv[4 * j2 + 1] += b0.y;
            vv[4 * j2 + 2] += b0.z; vv[4 * j2 + 3] += b0.w;
          }
        }
        if (relu)
#pragma unroll
          for (int j = 0; j < 16; ++j) vv[j] = fmaxf(vv[j], 0.0f);
        if (mode == 1) {
          float s = 0.0f;
#pragma unroll
          for (int j = 0; j < 16; ++j) { vv[j] = __expf(vv[j]); s += vv[j]; }
          rsum[sub] += s;
        } else if (mode == 2) {
          const float d = 1.0f / rowdiv[(size_t)z * SEQ + rowg];
#pragma unroll
          for (int j = 0; j < 16; ++j) vv[j] *= d;
        }
        *(int4*)(out8 + offC + (size_t)rowg * ldc + colg) = pack16_fp8(vv);
      }
    }
  }
  if (mode == 1 && lsum) {
    // lanes l and l^1 hold the same row; combine, one atomic per pair
#pragma unroll
    for (int sub = 0; sub < 2; ++sub) {
      float s = rsum[sub] + __shfl_xor(rsum[sub], 1);
      if (!(l & 1)) {
        const int rowg = m0 + wm + sub * 32 + rl0;
        atomicAdd(&lsum[(size_t)z * SEQ + rowg], s);
      }
    }
  }
}

// ---------------- cast x (fp32 -> fp8 e4m3), 16 elems/thread; last block zeroes lsum ----------------
__global__ void cast_x_f8(const float* __restrict__ in, unsigned char* __restrict__ out,
                          int n16, float* __restrict__ lsum) {
  int i = blockIdx.x * 256 + threadIdx.x;
  if (i >= n16) {
    if (blockIdx.x == (unsigned)(n16 / 256)) {   // the extra tail block
      float4 zv = {0.f, 0.f, 0.f, 0.f};
      float4* q = (float4*)lsum;                 // 32*SEQ floats = 8192 float4
#pragma unroll
      for (int j = 0; j < 32; ++j) q[threadIdx.x * 32 + j] = zv;
    }
    return;
  }
  const float4* p = (const float4*)in + (size_t)i * 4;
  float vv[16];
  *(f32x4*)&vv[0]  = *(const f32x4*)&p[0];
  *(f32x4*)&vv[4]  = *(const f32x4*)&p[1];
  *(f32x4*)&vv[8]  = *(const f32x4*)&p[2];
  *(f32x4*)&vv[12] = *(const f32x4*)&p[3];
  ((int4*)out)[i] = pack16_fp8(vv);
}

// ---------------- batched weight transpose+cast: fp32 [K][N] -> fp8 [N][K], 6 weights ----------------
struct WTList {
  const float* in[6];
  unsigned char* out[6];
  float scale[6];
  int K[6], N[6];
  int start[7];   // prefix sums of block counts
};
__global__ void transpose_cast_all(WTList L) {
  __shared__ float tile[32][33];
  int bid = blockIdx.x;
  int i = 0;
  while (bid >= L.start[i + 1]) ++i;
  int rel = bid - L.start[i];
  const int N = L.N[i], K = L.K[i];
  const int nx = N >> 5;
  const int n0 = (rel % nx) * 32, k0 = (rel / nx) * 32;
  const float* in = L.in[i];
  const float sc = L.scale[i];
  unsigned char* out = L.out[i];
  int tx = threadIdx.x, ty = threadIdx.y;
#pragma unroll
  for (int j = 0; j < 32; j += 8)
    tile[ty + j][tx] = in[(size_t)(k0 + ty + j) * N + n0 + tx];
  __syncthreads();
#pragma unroll
  for (int j = 0; j < 32; j += 8)
    out[(size_t)(n0 + ty + j) * K + k0 + tx] =
        (unsigned char)(pk_fp8_lo(tile[tx][ty + j] * sc, 0.f, 0) & 0xff);
}

// ---------------- split-K reduce + residual + bias + layernorm, one wave per row ----------------
__global__ void reduce_ln(const float* __restrict__ parts, int ns,
                          const float* __restrict__ res, const float* __restrict__ bias,
                          const float* __restrict__ gw, const float* __restrict__ bw,
                          float* __restrict__ outF, unsigned char* __restrict__ out8) {
  int l = threadIdx.x & 63, w = threadIdx.x >> 6;
  int row = blockIdx.x * 4 + w;
  const long long pstr = (long long)MTOK * EBD;
  float4 a = {0.f, 0.f, 0.f, 0.f}, b = {0.f, 0.f, 0.f, 0.f};
  for (int s = 0; s < ns; ++s) {
    const float4* p = (const float4*)(parts + s * pstr + (size_t)row * EBD);
    float4 pa = p[l], pb = p[l + 64];
    a.x += pa.x; a.y += pa.y; a.z += pa.z; a.w += pa.w;
    b.x += pb.x; b.y += pb.y; b.z += pb.z; b.w += pb.w;
  }
  {
    const float4* p = (const float4*)(res + (size_t)row * EBD);
    float4 pa = p[l], pb = p[l + 64];
    a.x += pa.x; a.y += pa.y; a.z += pa.z; a.w += pa.w;
    b.x += pb.x; b.y += pb.y; b.z += pb.z; b.w += pb.w;
  }
  if (bias) {
    const float4* p = (const float4*)bias;
    float4 pa = p[l], pb = p[l + 64];
    a.x += pa.x; a.y += pa.y; a.z += pa.z; a.w += pa.w;
    b.x += pb.x; b.y += pb.y; b.z += pb.z; b.w += pb.w;
  }
  float s = a.x + a.y + a.z + a.w + b.x + b.y + b.z + b.w;
  float q = a.x * a.x + a.y * a.y + a.z * a.z + a.w * a.w
          + b.x * b.x + b.y * b.y + b.z * b.z + b.w * b.w;
#pragma unroll
  for (int d = 1; d < 64; d <<= 1) { s += __shfl_xor(s, d); q += __shfl_xor(q, d); }
  float mu = s * (1.0f / EBD);
  float var = q * (1.0f / EBD) - mu * mu;
  float rs = rsqrtf(var + 1e-5f);
  const float4* g4 = (const float4*)gw;
  const float4* b4 = (const float4*)bw;
  float4 ga = g4[l], gb = g4[l + 64], ba = b4[l], bb = b4[l + 64];
  float4 o0, o1;
  o0.x = (a.x - mu) * rs * ga.x + ba.x;
  o0.y = (a.y - mu) * rs * ga.y + ba.y;
  o0.z = (a.z - mu) * rs * ga.z + ba.z;
  o0.w = (a.w - mu) * rs * ga.w + ba.w;
  o1.x = (b.x - mu) * rs * gb.x + bb.x;
  o1.y = (b.y - mu) * rs * gb.y + bb.y;
  o1.z = (b.z - mu) * rs * gb.z + bb.z;
  o1.w = (b.w - mu) * rs * gb.w + bb.w;
  if (outF) {
    float4* q4 = (float4*)(outF + (size_t)row * EBD);
    q4[l] = o0; q4[l + 64] = o1;
  }
  if (out8) {
    int* o = (int*)(out8 + (size_t)row * EBD);
    o[l]      = pk_fp8_hi(o0.z, o0.w, pk_fp8_lo(o0.x, o0.y, 0));
    o[l + 64] = pk_fp8_hi(o1.z, o1.w, pk_fp8_lo(o1.x, o1.y, 0));
  }
}

// ---------------- host-side orchestration ----------------
extern "C" void kernel_launch(void* const* d_in, const int* in_sizes, int n_in,
                              void* d_out, int out_size, void* d_ws, size_t ws_size,
                              hipStream_t stream) {
  const float* x  = (const float*)d_in[0];
  const float* Wq = (const float*)d_in[1];
  const float* Wk = (const float*)d_in[2];
  const float* Wv = (const float*)d_in[3];
  const float* Wo = (const float*)d_in[4];
  const float* g1 = (const float*)d_in[5];
  const float* b1 = (const float*)d_in[6];
  const float* g2 = (const float*)d_in[7];
  const float* b2 = (const float*)d_in[8];
  const float* W1 = (const float*)d_in[9];
  const float* c1 = (const float*)d_in[10];
  const float* W2 = (const float*)d_in[11];
  const float* c2 = (const float*)d_in[12];
  float* out = (float*)d_out;

  char* p = (char*)d_ws;
  auto take = [&](size_t bytes) { char* r = p; p += (bytes + 255) & ~(size_t)255; return r; };
  unsigned char* xb8    = (unsigned char*)take((size_t)MTOK * EBD);        //  2 MB
  unsigned char* qk8    = (unsigned char*)take((size_t)MTOK * 2 * HE);     // 32 MB [4096][8192]
  unsigned char* vT8    = (unsigned char*)take((size_t)32 * EBD * SEQ);    // 16 MB [(b,h)][e][s]
  unsigned char* sc8    = (unsigned char*)take((size_t)32 * SEQ * SEQ);    // 32 MB exp-scores (fp32 partials overlay later)
  float*         lsum   = (float*)        take((size_t)32 * SEQ * 4);      // 128 KB row sums
  unsigned char* ao8    = (unsigned char*)take((size_t)MTOK * HE);         // 16 MB O*16
  float*         nF     = (float*)        take((size_t)MTOK * EBD * 4);    //  8 MB
  unsigned char* n8     = (unsigned char*)take((size_t)MTOK * EBD);        //  2 MB
  unsigned char* h8     = (unsigned char*)take((size_t)MTOK * FFD);        //  8 MB
  unsigned char* Wqkv8T = (unsigned char*)take((size_t)3 * HE * EBD);      //  6 MB [12288][512]
  unsigned char* Wo8T   = (unsigned char*)take((size_t)EBD * HE);          //  2 MB [512][4096]
  unsigned char* W18T   = (unsigned char*)take((size_t)FFD * EBD);         //  1 MB [2048][512]
  unsigned char* W28T   = (unsigned char*)take((size_t)EBD * FFD);         //  1 MB [512][2048]
  float* parts = (float*)sc8;   // 32 MB fp32 split-K partials (sc8 dead after attn@V)

  auto gemmf8 = [&](const unsigned char* A, const unsigned char* Bt, float* oF,
                    unsigned char* o8, unsigned char* vTo, const float* rdiv,
                    const float* bias_, float* lsum_,
                    int Mm, int Nn, int Kk, int lda_, int ldb_, int ldc_,
                    long long bAb, long long bAh, long long bBb, long long bBh,
                    long long bCb, long long bCh, int zdiv_, int batch,
                    float sc_, int mode_, int relu_, int vmode_) {
    dim3 g(Nn / 128, Mm / 128, batch);
    gemm_f8<<<g, dim3(256), 0, stream>>>(A, Bt, oF, o8, vTo, rdiv, bias_, lsum_,
        lda_, ldb_, ldc_, Kk, bAb, bAh, bBb, bBh, bCb, bCh, zdiv_, sc_, mode_, relu_, vmode_);
  };

  // --- preprocessing: x -> fp8 (+ zero lsum); weights -> fp8 transposed (scaled) ---
  cast_x_f8<<<dim3(MTOK * EBD / 16 / 256 + 1), dim3(256), 0, stream>>>(
      x, xb8, MTOK * EBD / 16, lsum);
  {
    WTList L;
    const float* ins[6] = {Wq, Wk, Wv, Wo, W1, W2};
    unsigned char* outs[6] = {Wqkv8T, Wqkv8T + (size_t)HE * EBD, Wqkv8T + (size_t)2 * HE * EBD,
                              Wo8T, W18T, W28T};
    float scs[6] = {8.f, 8.f, 8.f, 16.f, 8.f, 16.f};
    int Ks[6] = {EBD, EBD, EBD, HE, EBD, FFD};
    int Ns[6] = {HE, HE, HE, EBD, FFD, EBD};
    int acc = 0;
    for (int i = 0; i < 6; ++i) {
      L.in[i] = ins[i]; L.out[i] = outs[i]; L.scale[i] = scs[i];
      L.K[i] = Ks[i]; L.N[i] = Ns[i]; L.start[i] = acc;
      acc += (Ks[i] / 32) * (Ns[i] / 32);
    }
    L.start[6] = acc;
    transpose_cast_all<<<dim3(acc), dim3(32, 8), 0, stream>>>(L);
  }

  // --- fused QKV (fp8): q,k -> qk8 [4096][8192]; V -> vT8 transposed; scale 1/8 ---
  gemmf8(xb8, Wqkv8T, nullptr, qk8, vT8, nullptr, nullptr, nullptr,
         MTOK, 3 * HE, EBD, EBD, EBD, 2 * HE,
         0, 0, 0, 0, 0, 0, 64, 1, 0.125f, 0, 0, 1);

  // --- exp-scores = exp(q.k/sqrt(E)) fp8 + atomic row sums, batched over 32 (b,h) ---
  const float qs = 0.04419417382415922f;  // 1/sqrt(512)
  gemmf8(qk8, qk8 + HE, nullptr, sc8, nullptr, nullptr, nullptr, lsum,
         SEQ, SEQ, EBD, 2 * HE, 2 * HE, SEQ,
         (long long)SEQ * 2 * HE, EBD, (long long)SEQ * 2 * HE, EBD,
         (long long)8 * SEQ * SEQ, (long long)SEQ * SEQ, 8, 32, qs, 1, 0, 0);

  // --- O = (exp-scores @ v) * 16 / l, fp8 out into ao8 [token][h*512+e] ---
  gemmf8(sc8, vT8, nullptr, ao8, nullptr, lsum, nullptr, nullptr,
         SEQ, EBD, SEQ, SEQ, SEQ, HE,
         (long long)8 * SEQ * SEQ, (long long)SEQ * SEQ,
         (long long)8 * EBD * SEQ, (long long)EBD * SEQ,
         (long long)SEQ * HE, (long long)EBD, 8, 32, 16.0f, 2, 0, 0);

  // --- O16 @ Wo16^T, split-K x4 (K=4096) -> fp32 partials (scale 1/256); reduce + x + LN1 ---
  gemmf8(ao8, Wo8T, parts, nullptr, nullptr, nullptr, nullptr, nullptr,
         MTOK, EBD, 1024, HE, HE, EBD,
         0, 1024, 0, 1024, 0, (long long)MTOK * EBD, 64, 4, 1.0f / 256.0f, 3, 0, 0);
  reduce_ln<<<dim3(MTOK / 4), dim3(256), 0, stream>>>(parts, 4, x, nullptr, g1, b1, nF, n8);

  // --- FF1 (fp8): h = relu(n @ W1x8 /8 + c1) -> h8 ---
  gemmf8(n8, W18T, nullptr, h8, nullptr, nullptr, c1, nullptr,
         MTOK, FFD, EBD, EBD, EBD, FFD,
         0, 0, 0, 0, 0, 0, 64, 1, 0.125f, 0, 1, 0);

  // --- FF2 (fp8): h8 @ W2x16, split-K x4 (K=2048) -> partials (scale 1/16); reduce + c2 + nF + LN2 ---
  gemmf8(h8, W28T, parts, nullptr, nullptr, nullptr, nullptr, nullptr,
         MTOK, EBD, 512, FFD, FFD, EBD,
         0, 512, 0, 512, 0, (long long)MTOK * EBD, 64, 4, 1.0f / 16.0f, 3, 0, 0);
  reduce_ln<<<dim3(MTOK / 4), dim3(256), 0, stream>>>(parts, 4, nF, c2, g2, b2, out, nullptr);
}